// Round 1
// baseline (387.944 us; speedup 1.0000x reference)
//
#include <hip/hip_runtime.h>

// SNN forward: x[B,1,28,28] -> permute to [T=28,B,28] -> Linear(28,32) -> IF
// -> Linear(32,10) -> IF -> mean spikes over T.
//
// Parallelization: 32 lanes per sample (lane = layer-1 neuron o).
//  - Images staged to LDS, transposed to [s][t][i] for contiguous b128 reads
//    (broadcast across the 32-lane sample group -> conflict-free).
//  - W1 row (28 f32) lives in VGPRs per lane.
//  - Layer-2 uses __ballot spike mask + nibble lookup tables in LDS:
//    h2[o2] = b2[o2] + sum_k Tbl[k][nibble_k(mask)][o2]   (8 LDS reads/t).
// block = 256 threads = 8 samples; LDS ~34 KB -> 4 blocks/CU, 16 waves/CU.

#define SPB     8
#define THREADS 256

__global__ __launch_bounds__(THREADS, 4) void snn_if_kernel(
    const float* __restrict__ x,    // [B][28][28]  (b, i, t) t fastest
    const float* __restrict__ W1,   // [32][28]
    const float* __restrict__ b1,   // [32]
    const float* __restrict__ W2,   // [10][32]
    const float* __restrict__ b2,   // [10]
    float* __restrict__ out,        // [B][10]
    int B)
{
    __shared__ __align__(16) float xT[SPB][28][32];  // [s][t][i], i padded 28->32
    __shared__ float Tbl[1280];                      // [k<8][nib<16][o2<10]

    const int tid = threadIdx.x;
    const int o   = tid & 31;    // neuron index (layer 1); also o2 for layer 2
    const int sl  = tid >> 5;    // local sample 0..7
    const int S0  = blockIdx.x * SPB;
    const int nS  = (B - S0 < SPB) ? (B - S0) : SPB;

    // ---- stage images: coalesced float4 reads, transposed scatter to LDS ----
    const float4* x4 = (const float4*)x + (size_t)S0 * 196;  // 196 float4 / image
    for (int f = tid; f < nS * 196; f += THREADS) {
        int s  = f / 196;
        int r  = f - s * 196;
        int i  = r / 7;          // row i (0..27)
        int tq = r - i * 7;      // float4 index within row -> t0 = 4*tq
        float4 v = x4[f];
        int t0 = tq * 4;
        xT[s][t0 + 0][i] = v.x;
        xT[s][t0 + 1][i] = v.y;
        xT[s][t0 + 2][i] = v.z;
        xT[s][t0 + 3][i] = v.w;
    }

    // ---- build layer-2 nibble tables: Tbl[(k*16+n)*10+o2] = sum_{j in n} W2[o2][4k+j]
    for (int e = tid; e < 1280; e += THREADS) {
        int o2 = e % 10;
        int tn = e / 10;         // 0..127
        int n  = tn & 15;
        int k  = tn >> 4;
        float v = 0.f;
        if (n & 1) v += W2[o2 * 32 + 4 * k + 0];
        if (n & 2) v += W2[o2 * 32 + 4 * k + 1];
        if (n & 4) v += W2[o2 * 32 + 4 * k + 2];
        if (n & 8) v += W2[o2 * 32 + 4 * k + 3];
        Tbl[e] = v;
    }

    // ---- per-lane weights in registers ----
    float w1r[28];
    {
        const float4* w4 = (const float4*)(W1 + o * 28);  // 112 B, 16B-aligned
        #pragma unroll
        for (int q = 0; q < 7; ++q) {
            float4 v = w4[q];
            w1r[4 * q + 0] = v.x; w1r[4 * q + 1] = v.y;
            w1r[4 * q + 2] = v.z; w1r[4 * q + 3] = v.w;
        }
    }
    const float b1o = b1[o];
    const float b2o = (o < 10) ? b2[o] : 0.f;

    __syncthreads();

    float v1 = 0.f, v2 = 0.f, cnt = 0.f;
    const float* xs = &xT[sl][0][0];

    for (int t = 0; t < 28; ++t) {
        // layer 1 dot: strict sequential i-order to track numpy f32 closely
        const float4* xr = (const float4*)(xs + t * 32);
        float acc = 0.f;
        #pragma unroll
        for (int q = 0; q < 7; ++q) {
            float4 a = xr[q];   // broadcast ds_read_b128 within sample group
            acc = fmaf(w1r[4 * q + 0], a.x, acc);
            acc = fmaf(w1r[4 * q + 1], a.y, acc);
            acc = fmaf(w1r[4 * q + 2], a.z, acc);
            acc = fmaf(w1r[4 * q + 3], a.w, acc);
        }
        v1 += acc + b1o;                       // v += h1
        bool sp = (v1 >= 1.0f);                // spike = H(v - 1)
        unsigned long long bal = __ballot(sp); // bit L = lane L's spike
        if (sp) v1 = 0.0f;                     // hard reset
        unsigned m = (unsigned)(bal >> (tid & 32)); // my half-wave's 32 bits

        if (o < 10) {
            // layer 2 via nibble tables
            float acc2 = 0.f;
            #pragma unroll
            for (int k = 0; k < 8; ++k) {
                unsigned nib = (m >> (4 * k)) & 15u;
                acc2 += Tbl[k * 160 + nib * 10 + o];
            }
            v2 += acc2 + b2o;                  // v += h2
            if (v2 >= 1.0f) { cnt += 1.0f; v2 = 0.0f; }
        }
    }

    if (o < 10 && (S0 + sl) < B) {
        out[(size_t)(S0 + sl) * 10 + o] = cnt / 28.0f;
    }
}

extern "C" void kernel_launch(void* const* d_in, const int* in_sizes, int n_in,
                              void* d_out, int out_size, void* d_ws, size_t ws_size,
                              hipStream_t stream) {
    const float* x  = (const float*)d_in[0];
    const float* W1 = (const float*)d_in[1];
    const float* b1 = (const float*)d_in[2];
    const float* W2 = (const float*)d_in[3];
    const float* b2 = (const float*)d_in[4];
    float* out = (float*)d_out;

    int B = in_sizes[0] / 784;           // 65536
    int grid = (B + SPB - 1) / SPB;      // 8192
    snn_if_kernel<<<grid, THREADS, 0, stream>>>(x, W1, b1, W2, b2, out, B);
}